// Round 9
// baseline (185.841 us; speedup 1.0000x reference)
//
#include <hip/hip_runtime.h>
#include <hip/hip_bf16.h>
#include <math.h>

#define NCLS 20
#define KDIM 128
#define ALPHA 0.7f
#define BETA 1.5f

// ws float layout:
// [0,2560) class sums | [2560,+20) counts(float) | [2580,+20) intra partials
// [2600,+20) hist(int) | [2620,+20) cursors(int) | [4096, +2N) int2 pairs
#define WS_SUMS 0
#define WS_CNT (NCLS * KDIM)
#define WS_INTRA (WS_CNT + NCLS)
#define WS_HIST (WS_INTRA + NCLS)
#define WS_CUR (WS_HIST + NCLS)
#define WS_ZERO_N (WS_CUR + NCLS)
#define WS_PAIRS 4096
#define WS_NEEDED ((WS_PAIRS + 2 * 262144) * 4)

#define GRID 2048

__global__ void k_init(float* ws) {
    const int tid = threadIdx.x;
    for (int i = tid; i < WS_ZERO_N; i += 256) ws[i] = 0.0f;
}

// ---- S1: class histogram (reads t only, int4) ----
__global__ void __launch_bounds__(256) k_hist(const int4* __restrict__ t4,
                                              float* __restrict__ ws, int N4) {
    __shared__ int h[NCLS];
    const int tid = threadIdx.x;
    if (tid < NCLS) h[tid] = 0;
    __syncthreads();
    const int gid = blockIdx.x * 256 + tid;
    if (gid < N4) {
        const int4 c = t4[gid];
        atomicAdd(&h[c.x], 1);
        atomicAdd(&h[c.y], 1);
        atomicAdd(&h[c.z], 1);
        atomicAdd(&h[c.w], 1);
    }
    __syncthreads();
    if (tid < NCLS) atomicAdd((int*)&ws[WS_HIST] + tid, h[tid]);
}

// ---- S2: 20-wide exclusive scan -> cursors; counts -> float ----
__global__ void k_scan(float* ws) {
    const int c = threadIdx.x;
    if (c < NCLS) {
        const int* h = (const int*)&ws[WS_HIST];
        int run = 0;
        for (int i = 0; i < NCLS; i++) run += (i < c) ? h[i] : 0;
        ((int*)&ws[WS_CUR])[c] = run;
        ws[WS_CNT + c] = (float)h[c];
    }
}

// ---- S3: scatter (class, idx) pairs into class-sorted order ----
__global__ void __launch_bounds__(256) k_scatter(const int4* __restrict__ t4,
                                                 float* ws, int N4) {
    __shared__ int h[NCLS], lbase[NCLS], lcur[NCLS];
    const int tid = threadIdx.x;
    if (tid < NCLS) { h[tid] = 0; lcur[tid] = 0; }
    __syncthreads();
    const int gid = blockIdx.x * 256 + tid;
    int4 c4 = make_int4(0, 0, 0, 0);
    if (gid < N4) {
        c4 = t4[gid];
        atomicAdd(&h[c4.x], 1);
        atomicAdd(&h[c4.y], 1);
        atomicAdd(&h[c4.z], 1);
        atomicAdd(&h[c4.w], 1);
    }
    __syncthreads();
    if (tid < NCLS) lbase[tid] = atomicAdd((int*)&ws[WS_CUR] + tid, h[tid]);
    __syncthreads();
    if (gid < N4) {
        int2* pairs = (int2*)&ws[WS_PAIRS];
        const int p0 = gid * 4;
        int cc[4] = {c4.x, c4.y, c4.z, c4.w};
#pragma unroll
        for (int j = 0; j < 4; j++) {
            const int c = cc[j];
            const int dst = lbase[c] + atomicAdd(&lcur[c], 1);
            pairs[dst] = make_int2(c, p0 + j);
        }
    }
}

// ---- pass 1: sorted segment-sum, ILP-restructured.
// Half-wave owns 32 sorted positions. Lane s loads pair base+s once
// (coalesced); idx/class broadcast per step via shfl; emb gathers issued in
// 8-deep independent batches (1KB coalesced each). Accumulate in registers;
// flush straight to global atomics on class change (~1 flush/half-wave). ----
#define SUMS_GRID 1024
__global__ void __launch_bounds__(256) k_sums(const float4* __restrict__ emb4,
                                              float* ws, int N) {
    const int tid = threadIdx.x;
    const int s = tid & 31;
    const int hw = blockIdx.x * 8 + (tid >> 5);
    const int base = hw * 32;
    if (base >= N) return;
    const int cnt = min(32, N - base);
    const int2* pairs = (const int2*)&ws[WS_PAIRS];
    const int2 myp = pairs[base + min(s, cnt - 1)];
    const int myc = myp.x;
    const int myi = myp.y;
    float* gs = &ws[WS_SUMS];

    float4 acc = make_float4(0.f, 0.f, 0.f, 0.f);
    int ccur = -1;
#define FLUSHG()                                              \
    {                                                         \
        float* a = &gs[ccur * KDIM + 4 * s];                  \
        unsafeAtomicAdd(a + 0, acc.x);                        \
        unsafeAtomicAdd(a + 1, acc.y);                        \
        unsafeAtomicAdd(a + 2, acc.z);                        \
        unsafeAtomicAdd(a + 3, acc.w);                        \
    }
#define MERGE(C, V)                                           \
    {                                                         \
        if ((C) != ccur) {                                    \
            if (ccur >= 0) FLUSHG();                          \
            ccur = (C);                                       \
            acc = (V);                                        \
        } else {                                              \
            acc.x += (V).x; acc.y += (V).y;                   \
            acc.z += (V).z; acc.w += (V).w;                   \
        }                                                     \
    }

    if (cnt == 32) {
        for (int j0 = 0; j0 < 32; j0 += 8) {
            float4 v0, v1, v2, v3, v4, v5, v6, v7;
            int c0, c1, c2, c3, c4, c5, c6, c7;
#define G(jj) { const int idx = __shfl(myi, j0 + jj, 32);                 \
                v##jj = emb4[(size_t)idx * 32 + s];                       \
                c##jj = __shfl(myc, j0 + jj, 32); }
            G(0) G(1) G(2) G(3) G(4) G(5) G(6) G(7)
#undef G
            MERGE(c0, v0) MERGE(c1, v1) MERGE(c2, v2) MERGE(c3, v3)
            MERGE(c4, v4) MERGE(c5, v5) MERGE(c6, v6) MERGE(c7, v7)
        }
    } else {
        for (int j = 0; j < cnt; j++) {
            const int idx = __shfl(myi, j, 32);
            const float4 v = emb4[(size_t)idx * 32 + s];
            const int c = __shfl(myc, j, 32);
            MERGE(c, v)
        }
    }
    if (ccur >= 0) FLUSHG();
#undef MERGE
#undef FLUSHG
}

// ---- fallback pass 1 (R6-proven; used only if ws too small) ----
#define FB_BLK 128
#define FB_GRID 2048
__global__ void __launch_bounds__(FB_BLK) k_sums_fb(const float4* __restrict__ emb4,
                                                    const int* __restrict__ t,
                                                    float* ws, int N) {
    __shared__ float lsum[2][NCLS * KDIM];
    __shared__ float lcnt[NCLS];
    __shared__ int lds_t[FB_BLK];
    const int tid = threadIdx.x;
    const int w = tid >> 6, k = tid & 63;
    const int half = k >> 5;
    const int k31 = k & 31;
    for (int i = tid; i < 2 * NCLS * KDIM; i += FB_BLK) (&lsum[0][0])[i] = 0.0f;
    if (tid < NCLS) lcnt[tid] = 0.0f;
    __syncthreads();
    const int chunk = blockIdx.x * FB_BLK;
    const int npts = min(FB_BLK, N - chunk);
    if (tid < npts) {
        const int c = t[chunk + tid];
        lds_t[tid] = c;
        unsafeAtomicAdd(&lcnt[c], 1.0f);
    }
    __syncthreads();
    float* L = lsum[w];
    for (int q = 32 * w; q < 32 * w + 32; q++) {
        const int pl = 2 * q + half;
        if (pl < npts) {
            const int c = lds_t[pl];
            const float4 v = emb4[(size_t)(chunk + pl) * 32 + k31];
            const int cA = __shfl(c, 0, 64);
            const int cB = __shfl(c, 32, 64);
            if (cA == cB) {
                float4 vv;
                vv.x = v.x + __shfl_xor(v.x, 32, 64);
                vv.y = v.y + __shfl_xor(v.y, 32, 64);
                vv.z = v.z + __shfl_xor(v.z, 32, 64);
                vv.w = v.w + __shfl_xor(v.w, 32, 64);
                if (half == 0) {
                    float4* a = (float4*)&L[cA * KDIM + 4 * k31];
                    float4 o = *a;
                    o.x += vv.x; o.y += vv.y; o.z += vv.z; o.w += vv.w;
                    *a = o;
                }
            } else {
                float4* a = (float4*)&L[c * KDIM + 4 * k31];
                float4 o = *a;
                o.x += v.x; o.y += v.y; o.z += v.z; o.w += v.w;
                *a = o;
            }
        }
    }
    __syncthreads();
    for (int i = tid; i < NCLS * KDIM; i += FB_BLK)
        unsafeAtomicAdd(&ws[WS_SUMS + i], lsum[0][i] + lsum[1][i]);
    if (tid < NCLS) unsafeAtomicAdd(&ws[WS_CNT + tid], lcnt[tid]);
}

// ---- pass 2 (proven; unchanged) ----
__global__ void __launch_bounds__(256) k_intra(const float4* __restrict__ emb4,
                                               const int* __restrict__ t,
                                               const float* __restrict__ pts,
                                               float* ws, int N) {
    __shared__ float lmean[NCLS * KDIM];
    __shared__ float lintra[NCLS];
    const int tid = threadIdx.x;
    for (int i = tid; i < NCLS * KDIM; i += 256) {
        float cnt = ws[WS_CNT + i / KDIM];
        lmean[i] = ws[WS_SUMS + i] / fmaxf(cnt, 1.0f);
    }
    if (tid < NCLS) lintra[tid] = 0.0f;
    __syncthreads();

    const int s = tid & 31;
    const int pp = tid >> 5;
    const int stride = GRID * 8;
    for (int p = blockIdx.x * 8 + pp; p < N; p += 2 * stride) {
        const int p1 = p + stride;
        {
            const int c = t[p];
            const float4 v = emb4[(size_t)p * 32 + s];
            const float4 m = *(const float4*)&lmean[c * KDIM + 4 * s];
            float dx = v.x - m.x, dy = v.y - m.y, dz = v.z - m.z, dw = v.w - m.w;
            float d2 = dx * dx + dy * dy + dz * dz + dw * dw;
            for (int off = 16; off >= 1; off >>= 1) d2 += __shfl_down(d2, off, 32);
            if (s == 0) {
                float d = sqrtf(d2);
                float px = pts[(size_t)p * 3 + 0];
                float py = pts[(size_t)p * 3 + 1];
                float pz = pts[(size_t)p * 3 + 2];
                float r = sqrtf(px * px + py * py + pz * pz);
                float g = 1.0f / (1.0f + expf(-r));
                float h = fmaxf(d - ALPHA, 0.0f);
                unsafeAtomicAdd(&lintra[c], g * h * h);
            }
        }
        if (p1 < N) {
            const int c = t[p1];
            const float4 v = emb4[(size_t)p1 * 32 + s];
            const float4 m = *(const float4*)&lmean[c * KDIM + 4 * s];
            float dx = v.x - m.x, dy = v.y - m.y, dz = v.z - m.z, dw = v.w - m.w;
            float d2 = dx * dx + dy * dy + dz * dz + dw * dw;
            for (int off = 16; off >= 1; off >>= 1) d2 += __shfl_down(d2, off, 32);
            if (s == 0) {
                float d = sqrtf(d2);
                float px = pts[(size_t)p1 * 3 + 0];
                float py = pts[(size_t)p1 * 3 + 1];
                float pz = pts[(size_t)p1 * 3 + 2];
                float r = sqrtf(px * px + py * py + pz * pz);
                float g = 1.0f / (1.0f + expf(-r));
                float h = fmaxf(d - ALPHA, 0.0f);
                unsafeAtomicAdd(&lintra[c], g * h * h);
            }
        }
    }
    __syncthreads();
    if (tid < NCLS) unsafeAtomicAdd(&ws[WS_INTRA + tid], lintra[tid]);
}

// ---- final (unchanged) ----
__global__ void __launch_bounds__(256) k_final(const float* ws, float* out) {
    __shared__ float lmean[NCLS * KDIM];
    __shared__ float red[256];
    const int tid = threadIdx.x;
    for (int i = tid; i < NCLS * KDIM; i += 256) {
        float cnt = ws[WS_CNT + i / KDIM];
        lmean[i] = ws[WS_SUMS + i] / fmaxf(cnt, 1.0f);
    }
    __syncthreads();

    float acc = 0.0f;
    for (int idx = tid; idx < 361; idx += 256) {
        int i = idx / 19 + 1;
        int j = idx % 19 + 1;
        if (i != j) {
            float sq = 0.0f;
            const float* mi = lmean + i * KDIM;
            const float* mj = lmean + j * KDIM;
            for (int k = 0; k < KDIM; k++) {
                float df = mi[k] - mj[k];
                sq += df * df;
            }
            float dist = sqrtf(sq);
            float h = fmaxf(BETA - dist, 0.0f);
            acc += h * h;
        }
    }
    red[tid] = acc;
    __syncthreads();
    for (int st = 128; st >= 1; st >>= 1) {
        if (tid < st) red[tid] += red[tid + st];
        __syncthreads();
    }
    if (tid == 0) {
        float intra = 0.0f;
        for (int c = 1; c < NCLS; c++) {
            intra += ws[WS_INTRA + c] / fmaxf(ws[WS_CNT + c], 1.0f);
        }
        out[0] = intra / (float)NCLS + red[0] / (float)(NCLS * (NCLS - 1));
    }
}

extern "C" void kernel_launch(void* const* d_in, const int* in_sizes, int n_in,
                              void* d_out, int out_size, void* d_ws, size_t ws_size,
                              hipStream_t stream) {
    const float* pts = (const float*)d_in[0];
    const int* t = (const int*)d_in[1];
    const int4* t4 = (const int4*)d_in[1];
    const float4* emb4 = (const float4*)d_in[2];
    float* out = (float*)d_out;
    float* ws = (float*)d_ws;
    const int N = in_sizes[1];
    const int N4 = N / 4;

    k_init<<<1, 256, 0, stream>>>(ws);

    if (ws_size >= (size_t)WS_NEEDED && (N % 4) == 0) {
        k_hist<<<(N4 + 255) / 256, 256, 0, stream>>>(t4, ws, N4);
        k_scan<<<1, 64, 0, stream>>>(ws);
        k_scatter<<<(N4 + 255) / 256, 256, 0, stream>>>(t4, ws, N4);
        k_sums<<<SUMS_GRID, 256, 0, stream>>>(emb4, ws, N);
    } else {
        k_sums_fb<<<FB_GRID, FB_BLK, 0, stream>>>(emb4, t, ws, N);
    }
    k_intra<<<GRID, 256, 0, stream>>>(emb4, t, pts, ws, N);
    k_final<<<1, 256, 0, stream>>>(ws, out);
}

// Round 10
// 172.231 us; speedup vs baseline: 1.0790x; 1.0790x over previous
//
#include <hip/hip_runtime.h>
#include <hip/hip_bf16.h>
#include <math.h>

#define NCLS 20
#define KDIM 128
#define ALPHA 0.7f
#define BETA 1.5f

// ws float layout: [0,2560) class sums | [2560,+20) counts | [2580,+20) intra
#define WS_SUMS 0
#define WS_CNT (NCLS * KDIM)
#define WS_INTRA (WS_CNT + NCLS)
#define WS_ZERO_N (WS_INTRA + NCLS)

#define GRID 2048
#define SUMS_GRID 1024

__global__ void k_init(float* ws) {
    const int tid = threadIdx.x;
    for (int i = tid; i < WS_ZERO_N; i += 256) ws[i] = 0.0f;
}

// ---- counts: plain histogram on t (1 MB) ----
__global__ void __launch_bounds__(256) k_hist(const int* __restrict__ t,
                                              float* __restrict__ ws, int N) {
    __shared__ int h[NCLS];
    const int tid = threadIdx.x;
    if (tid < NCLS) h[tid] = 0;
    __syncthreads();
    const int gid = blockIdx.x * 256 + tid;
    if (gid < N) atomicAdd(&h[t[gid]], 1);
    __syncthreads();
    if (tid < NCLS) unsafeAtomicAdd(&ws[WS_CNT + tid], (float)h[tid]);
}

// ---- pass 1: select-accumulate segment sum.
// k_intra's proven load shape (256 thr = 8 point-slots, strided float4).
// Per point: 20-way fully-unrolled compare-masked FMA into 20 float4
// register accumulators. NO per-point scatter (no LDS ops, no atomics, no
// dynamic indexing). Flush: shfl_xor(32) pair-combine -> LDS atomics ->
// one 2560-wide global-atomic flush per block (2.6M total, R8-proven). ----
__global__ void __launch_bounds__(256) k_sums_sel(const float4* __restrict__ emb4,
                                                  const int* __restrict__ t,
                                                  float* __restrict__ ws, int N) {
    __shared__ float lsum[NCLS * KDIM];
    const int tid = threadIdx.x;
    for (int i = tid; i < NCLS * KDIM; i += 256) lsum[i] = 0.0f;
    __syncthreads();

    const int s = tid & 31;    // dim-quad within point
    const int pp = tid >> 5;   // point-slot 0..7
    const int stride = SUMS_GRID * 8;

    float4 acc[NCLS];
#pragma unroll
    for (int c = 0; c < NCLS; c++) acc[c] = make_float4(0.f, 0.f, 0.f, 0.f);

    for (int p = blockIdx.x * 8 + pp; p < N; p += stride) {
        const int c = t[p];
        const float4 v = emb4[(size_t)p * 32 + s];
#pragma unroll
        for (int cls = 0; cls < NCLS; cls++) {
            const float m = (c == cls) ? 1.0f : 0.0f;
            acc[cls].x = fmaf(m, v.x, acc[cls].x);
            acc[cls].y = fmaf(m, v.y, acc[cls].y);
            acc[cls].z = fmaf(m, v.z, acc[cls].z);
            acc[cls].w = fmaf(m, v.w, acc[cls].w);
        }
    }

    // combine the two point-slots sharing a wave (tid <-> tid^32)
#pragma unroll
    for (int cls = 0; cls < NCLS; cls++) {
        acc[cls].x += __shfl_xor(acc[cls].x, 32, 64);
        acc[cls].y += __shfl_xor(acc[cls].y, 32, 64);
        acc[cls].z += __shfl_xor(acc[cls].z, 32, 64);
        acc[cls].w += __shfl_xor(acc[cls].w, 32, 64);
    }
    if ((tid & 63) < 32) {
#pragma unroll
        for (int cls = 0; cls < NCLS; cls++) {
            float* a = &lsum[cls * KDIM + 4 * s];
            unsafeAtomicAdd(a + 0, acc[cls].x);
            unsafeAtomicAdd(a + 1, acc[cls].y);
            unsafeAtomicAdd(a + 2, acc[cls].z);
            unsafeAtomicAdd(a + 3, acc[cls].w);
        }
    }
    __syncthreads();

    for (int i = tid; i < NCLS * KDIM; i += 256)
        if (lsum[i] != 0.0f) unsafeAtomicAdd(&ws[WS_SUMS + i], lsum[i]);
}

// ---- pass 2 (proven; unchanged) ----
__global__ void __launch_bounds__(256) k_intra(const float4* __restrict__ emb4,
                                               const int* __restrict__ t,
                                               const float* __restrict__ pts,
                                               float* __restrict__ ws, int N) {
    __shared__ float lmean[NCLS * KDIM];
    __shared__ float lintra[NCLS];
    const int tid = threadIdx.x;
    for (int i = tid; i < NCLS * KDIM; i += 256) {
        float cnt = ws[WS_CNT + i / KDIM];
        lmean[i] = ws[WS_SUMS + i] / fmaxf(cnt, 1.0f);
    }
    if (tid < NCLS) lintra[tid] = 0.0f;
    __syncthreads();

    const int s = tid & 31;
    const int pp = tid >> 5;
    const int stride = GRID * 8;
    for (int p = blockIdx.x * 8 + pp; p < N; p += 2 * stride) {
        const int p1 = p + stride;
        {
            const int c = t[p];
            const float4 v = emb4[(size_t)p * 32 + s];
            const float4 m = *(const float4*)&lmean[c * KDIM + 4 * s];
            float dx = v.x - m.x, dy = v.y - m.y, dz = v.z - m.z, dw = v.w - m.w;
            float d2 = dx * dx + dy * dy + dz * dz + dw * dw;
            for (int off = 16; off >= 1; off >>= 1) d2 += __shfl_down(d2, off, 32);
            if (s == 0) {
                float d = sqrtf(d2);
                float px = pts[(size_t)p * 3 + 0];
                float py = pts[(size_t)p * 3 + 1];
                float pz = pts[(size_t)p * 3 + 2];
                float r = sqrtf(px * px + py * py + pz * pz);
                float g = 1.0f / (1.0f + expf(-r));
                float h = fmaxf(d - ALPHA, 0.0f);
                unsafeAtomicAdd(&lintra[c], g * h * h);
            }
        }
        if (p1 < N) {
            const int c = t[p1];
            const float4 v = emb4[(size_t)p1 * 32 + s];
            const float4 m = *(const float4*)&lmean[c * KDIM + 4 * s];
            float dx = v.x - m.x, dy = v.y - m.y, dz = v.z - m.z, dw = v.w - m.w;
            float d2 = dx * dx + dy * dy + dz * dz + dw * dw;
            for (int off = 16; off >= 1; off >>= 1) d2 += __shfl_down(d2, off, 32);
            if (s == 0) {
                float d = sqrtf(d2);
                float px = pts[(size_t)p1 * 3 + 0];
                float py = pts[(size_t)p1 * 3 + 1];
                float pz = pts[(size_t)p1 * 3 + 2];
                float r = sqrtf(px * px + py * py + pz * pz);
                float g = 1.0f / (1.0f + expf(-r));
                float h = fmaxf(d - ALPHA, 0.0f);
                unsafeAtomicAdd(&lintra[c], g * h * h);
            }
        }
    }
    __syncthreads();
    if (tid < NCLS) unsafeAtomicAdd(&ws[WS_INTRA + tid], lintra[tid]);
}

// ---- final (unchanged) ----
__global__ void __launch_bounds__(256) k_final(const float* __restrict__ ws,
                                               float* __restrict__ out) {
    __shared__ float lmean[NCLS * KDIM];
    __shared__ float red[256];
    const int tid = threadIdx.x;
    for (int i = tid; i < NCLS * KDIM; i += 256) {
        float cnt = ws[WS_CNT + i / KDIM];
        lmean[i] = ws[WS_SUMS + i] / fmaxf(cnt, 1.0f);
    }
    __syncthreads();

    float acc = 0.0f;
    for (int idx = tid; idx < 361; idx += 256) {
        int i = idx / 19 + 1;
        int j = idx % 19 + 1;
        if (i != j) {
            float sq = 0.0f;
            const float* mi = lmean + i * KDIM;
            const float* mj = lmean + j * KDIM;
            for (int k = 0; k < KDIM; k++) {
                float df = mi[k] - mj[k];
                sq += df * df;
            }
            float dist = sqrtf(sq);
            float h = fmaxf(BETA - dist, 0.0f);
            acc += h * h;
        }
    }
    red[tid] = acc;
    __syncthreads();
    for (int st = 128; st >= 1; st >>= 1) {
        if (tid < st) red[tid] += red[tid + st];
        __syncthreads();
    }
    if (tid == 0) {
        float intra = 0.0f;
        for (int c = 1; c < NCLS; c++) {
            intra += ws[WS_INTRA + c] / fmaxf(ws[WS_CNT + c], 1.0f);
        }
        out[0] = intra / (float)NCLS + red[0] / (float)(NCLS * (NCLS - 1));
    }
}

extern "C" void kernel_launch(void* const* d_in, const int* in_sizes, int n_in,
                              void* d_out, int out_size, void* d_ws, size_t ws_size,
                              hipStream_t stream) {
    const float* pts = (const float*)d_in[0];
    const int* t = (const int*)d_in[1];
    const float4* emb4 = (const float4*)d_in[2];
    float* out = (float*)d_out;
    float* ws = (float*)d_ws;
    const int N = in_sizes[1];

    k_init<<<1, 256, 0, stream>>>(ws);
    k_hist<<<(N + 255) / 256, 256, 0, stream>>>(t, ws, N);
    k_sums_sel<<<SUMS_GRID, 256, 0, stream>>>(emb4, t, ws, N);
    k_intra<<<GRID, 256, 0, stream>>>(emb4, t, pts, ws, N);
    k_final<<<1, 256, 0, stream>>>(ws, out);
}